// Round 13
// baseline (3273.614 us; speedup 1.0000x reference)
//
#include <hip/hip_runtime.h>
#include <hip/hip_bf16.h>

#define B_ 256
#define T_ 512
#define F_ 8
#define H_ 512
#define OUT_ 96

// 16 batch-clusters x (8 workgroups x 4 waves). Each wave owns 16 h-cols
// (48 gate-cols), W slice register-resident. 128 blocks of 256 thr =>
// co-residency guaranteed by capacity. Exchange: TAGGED u64 WORDS via
// compiler-lowered relaxed AGENT-scope atomics (the proven-coherent primitive
// from rounds 3-8). u64 = two (tag<<16|bf16) words -> data IS the signal:
// no flags, no acquire fences, no vmcnt drains on the critical path.
// Parity double-buffered; skew provably <= 1 step.
#define NCL 16
#define BT 16
#define NWG 8

typedef __attribute__((ext_vector_type(8))) short short8;
typedef __attribute__((ext_vector_type(4))) float f32x4;

// [buf][cluster][row 0..15][colpair 0..255] : u64 = 2 tagged cols. 2 MB, L3-res.
__device__ unsigned long long g_ht[2][NCL][16][256];

__device__ __forceinline__ short f2bf(float v) {
  __hip_bfloat16 b = __float2bfloat16(v);
  unsigned short u;
  __builtin_memcpy(&u, &b, 2);
  return (short)u;
}

__global__ void init_ht() {
  int i = blockIdx.x * 256 + (int)threadIdx.x;  // 0..131071
  unsigned long long* p = &g_ht[0][0][0][0];
  __hip_atomic_store(&p[i], 0ull, __ATOMIC_RELAXED, __HIP_MEMORY_SCOPE_AGENT);
}

__global__ __launch_bounds__(256, 1) void gru_persistent(
    const float* x, const float* w_ih, const float* w_hh,
    const float* bias_ih, const float* bias_hh,
    const float* fc_w, const float* fc_b, float* out) {
  const int tid = (int)threadIdx.x;
  const int w = tid >> 6;
  const int lane = tid & 63;
  const int l15 = lane & 15;
  const int lg = lane >> 4;
  const int bid = (int)blockIdx.x;
  const int cl = bid & 15;   // cluster
  const int wgj = bid >> 4;  // wg within cluster
  const int rb0 = cl * BT;
  const int c0 = wgj * 64 + w * 16;

  __shared__ short8 h_lds[1024];    // [chunk*16 + localrow] 16B (16 KB), single buf
  __shared__ short t_hw[4][16][20]; // per-wave transpose tiles (proven in r9)

  // ---- W fragments, register-resident for all 512 steps ----
  short8 wfrag[3][17];
#pragma unroll
  for (int g = 0; g < 3; ++g) {
    const float* wr = w_hh + (size_t)(g * H_ + c0 + l15) * H_ + lg * 8;
#pragma unroll
    for (int kk = 0; kk < 16; ++kk) {
      f32x4 a = ((const f32x4*)(wr + kk * 32))[0];
      f32x4 b2 = ((const f32x4*)(wr + kk * 32))[1];
      short8 o;
#pragma unroll
      for (int j = 0; j < 4; ++j) { o[j] = f2bf(a[j]); o[4 + j] = f2bf(b2[j]); }
      wfrag[g][kk] = o;
    }
    short8 o = {0, 0, 0, 0, 0, 0, 0, 0};
    if (lg == 0) {  // k = 512..519 -> W_ih row
      const f32x4* wi = (const f32x4*)(w_ih + (size_t)(g * H_ + c0 + l15) * F_);
      f32x4 a = wi[0], b2 = wi[1];
#pragma unroll
      for (int j = 0; j < 4; ++j) { o[j] = f2bf(a[j]); o[4 + j] = f2bf(b2[j]); }
    }
    wfrag[g][16] = o;
  }

  const int colh = c0 + l15;
  const float b_r = bias_ih[colh] + bias_hh[colh];
  const float b_z = bias_ih[H_ + colh] + bias_hh[H_ + colh];
  const float bin_ = bias_ih[2 * H_ + colh];
  const float bhn_ = bias_hh[2 * H_ + colh];

  float hown[4] = {0.f, 0.f, 0.f, 0.f};
  bool gaveup = false;

  const float* xrow = x + (size_t)(rb0 + l15) * T_ * F_;

  // gather geometry: thread owns local row = tid&15, colpairs (tid>>4)*4 + r4*64 + k
  const int grow = tid & 15;
  const int gcp = (tid >> 4) * 4;
  // publish geometry: lane -> local row = lane>>2, cols c0 + (lane&3)*4 .. +3
  const int prow = lane >> 2;
  const int pcp = (c0 >> 1) + (lane & 3) * 2;  // colpair base (2 u64 per lane)

  // x prefetch for t=0
  f32x4 xa = ((const f32x4*)xrow)[0];
  f32x4 xb2 = ((const f32x4*)xrow)[1];

  for (int t = 0; t < T_; ++t) {
    if (t > 0) {
      // ---- spin-gather: 16 tagged u64 atomic loads until all 32 tags == t ----
      const unsigned long long tagw = (unsigned long long)t;
      const int buf = t & 1;
      unsigned long long vv[16];
      if (!gaveup) {
        unsigned spins = 0;
        for (;;) {
          unsigned long long bad = 0;
#pragma unroll
          for (int i = 0; i < 16; ++i) {
            const int r4 = i >> 2, k = i & 3;
            vv[i] = __hip_atomic_load(&g_ht[buf][cl][grow][gcp + r4 * 64 + k],
                                      __ATOMIC_RELAXED, __HIP_MEMORY_SCOPE_AGENT);
            bad |= (((vv[i] >> 16) ^ tagw) & 0xFFFFull) | ((vv[i] >> 48) ^ tagw);
          }
          if (!bad) break;
          if (++spins > (1u << 20)) { gaveup = true; break; }
          __builtin_amdgcn_s_sleep(1);
        }
      } else {
#pragma unroll
        for (int i = 0; i < 16; ++i) {
          const int r4 = i >> 2, k = i & 3;
          vv[i] = __hip_atomic_load(&g_ht[buf][cl][grow][gcp + r4 * 64 + k],
                                    __ATOMIC_RELAXED, __HIP_MEMORY_SCOPE_AGENT);
        }
      }
      // unpack low 16b of each 32b half -> lane-linear LDS
#pragma unroll
      for (int r4 = 0; r4 < 4; ++r4) {
        short8 o;
#pragma unroll
        for (int j = 0; j < 8; ++j)
          o[j] = (short)(vv[r4 * 4 + (j >> 1)] >> (32 * (j & 1)));
        h_lds[r4 * 256 + tid] = o;
      }
    }

    // x fragment from prefetched registers
    short8 xf;
#pragma unroll
    for (int j = 0; j < 4; ++j) { xf[j] = f2bf(xa[j]); xf[4 + j] = f2bf(xb2[j]); }

    __syncthreads();  // the ONLY barrier per step (gather writes -> frag reads)

    // prefetch x for t+1 (overlaps MFMA)
    {
      const int tn = (t + 1 < T_) ? t + 1 : T_ - 1;
      xa = ((const f32x4*)(xrow + (size_t)tn * F_))[0];
      xb2 = ((const f32x4*)(xrow + (size_t)tn * F_))[1];
    }

    // ---- MFMAs: 3 gates per kk ----
    f32x4 acc_r = {0.f, 0.f, 0.f, 0.f}, acc_z = {0.f, 0.f, 0.f, 0.f};
    f32x4 acc_nh = {0.f, 0.f, 0.f, 0.f}, acc_nx = {0.f, 0.f, 0.f, 0.f};
    if (t > 0) {
#pragma unroll
      for (int kk = 0; kk < 16; ++kk) {
        short8 a = h_lds[(kk * 4 + lg) * 16 + l15];
        acc_r = __builtin_amdgcn_mfma_f32_16x16x32_bf16(a, wfrag[0][kk], acc_r, 0, 0, 0);
        acc_z = __builtin_amdgcn_mfma_f32_16x16x32_bf16(a, wfrag[1][kk], acc_z, 0, 0, 0);
        acc_nh = __builtin_amdgcn_mfma_f32_16x16x32_bf16(a, wfrag[2][kk], acc_nh, 0, 0, 0);
      }
    }
    acc_r = __builtin_amdgcn_mfma_f32_16x16x32_bf16(xf, wfrag[0][16], acc_r, 0, 0, 0);
    acc_z = __builtin_amdgcn_mfma_f32_16x16x32_bf16(xf, wfrag[1][16], acc_z, 0, 0, 0);
    acc_nx = __builtin_amdgcn_mfma_f32_16x16x32_bf16(xf, wfrag[2][16], acc_nx, 0, 0, 0);

    // ---- gates + fp32-carry state update ----
    short hnew[4];
#pragma unroll
    for (int q = 0; q < 4; ++q) {
      float pr = acc_r[q] + b_r;
      float pz = acc_z[q] + b_z;
      float r = 1.f / (1.f + __expf(-pr));
      float z = 1.f / (1.f + __expf(-pz));
      float n = tanhf(acc_nx[q] + bin_ + r * (acc_nh[q] + bhn_));
      hown[q] = n + z * (hown[q] - n);
      hnew[q] = f2bf(hown[q]);
    }

    // ---- wave-local transpose (same-wave lgkmcnt ordering, proven r9) ----
#pragma unroll
    for (int q = 0; q < 4; ++q) t_hw[w][4 * lg + q][l15] = hnew[q];
    // ---- publish: two tagged u64 atomic stores per lane; data IS the signal ----
    {
      unsigned long long v;
      __builtin_memcpy(&v, &t_hw[w][prow][(lane & 3) * 4], 8);
      const unsigned long long tg = (unsigned long long)(t + 1) << 16;
      unsigned long long w0 = (tg | (v & 0xFFFFull)) |
                              ((tg | ((v >> 16) & 0xFFFFull)) << 32);
      unsigned long long w1 = (tg | ((v >> 32) & 0xFFFFull)) |
                              ((tg | ((v >> 48) & 0xFFFFull)) << 32);
      const int pbuf = (t + 1) & 1;
      __hip_atomic_store(&g_ht[pbuf][cl][prow][pcp], w0, __ATOMIC_RELAXED,
                         __HIP_MEMORY_SCOPE_AGENT);
      __hip_atomic_store(&g_ht[pbuf][cl][prow][pcp + 1], w1, __ATOMIC_RELAXED,
                         __HIP_MEMORY_SCOPE_AGENT);
    }
    // no drain, no flag — next spin self-synchronizes
  }

  // ---- final FC: wgs 0..1 of each cluster hold the 6 FC waves ----
  if (wgj >= 2) return;
  {
    const unsigned long long tagw = (unsigned long long)T_;
    unsigned long long vv[16];
    unsigned spins = 0;
    for (;;) {
      unsigned long long bad = 0;
#pragma unroll
      for (int i = 0; i < 16; ++i) {
        const int r4 = i >> 2, k = i & 3;
        vv[i] = __hip_atomic_load(&g_ht[0][cl][grow][gcp + r4 * 64 + k],
                                  __ATOMIC_RELAXED, __HIP_MEMORY_SCOPE_AGENT);
        bad |= (((vv[i] >> 16) ^ tagw) & 0xFFFFull) | ((vv[i] >> 48) ^ tagw);
      }
      if (!bad) break;
      if (++spins > (1u << 20)) break;
      __builtin_amdgcn_s_sleep(1);
    }
#pragma unroll
    for (int r4 = 0; r4 < 4; ++r4) {
      short8 o;
#pragma unroll
      for (int j = 0; j < 8; ++j)
        o[j] = (short)(vv[r4 * 4 + (j >> 1)] >> (32 * (j & 1)));
      h_lds[r4 * 256 + tid] = o;
    }
  }
  __syncthreads();
  const int wi = wgj * 4 + w;
  if (wi >= OUT_ / 16) return;
  short8 afrag[16];
#pragma unroll
  for (int kk = 0; kk < 16; ++kk) afrag[kk] = h_lds[(kk * 4 + lg) * 16 + l15];
  const int col = wi * 16 + l15;
  const float* wrow = fc_w + (size_t)col * H_ + lg * 8;
  f32x4 acc = {0.f, 0.f, 0.f, 0.f};
#pragma unroll
  for (int kk = 0; kk < 16; ++kk) {
    f32x4 a = ((const f32x4*)(wrow + kk * 32))[0];
    f32x4 b2 = ((const f32x4*)(wrow + kk * 32))[1];
    short8 bfr;
#pragma unroll
    for (int j = 0; j < 4; ++j) { bfr[j] = f2bf(a[j]); bfr[4 + j] = f2bf(b2[j]); }
    acc = __builtin_amdgcn_mfma_f32_16x16x32_bf16(afrag[kk], bfr, acc, 0, 0, 0);
  }
  const float fb = fc_b[col];
#pragma unroll
  for (int q = 0; q < 4; ++q) {
    int row_o = rb0 + lg * 4 + q;
    out[(size_t)row_o * OUT_ + col] = acc[q] + fb;
  }
}

extern "C" void kernel_launch(void* const* d_in, const int* in_sizes, int n_in,
                              void* d_out, int out_size, void* d_ws, size_t ws_size,
                              hipStream_t stream) {
  const float* x = (const float*)d_in[0];
  const float* w_ih = (const float*)d_in[1];
  const float* w_hh = (const float*)d_in[2];
  const float* b_ih = (const float*)d_in[3];
  const float* b_hh = (const float*)d_in[4];
  const float* fc_w = (const float*)d_in[5];
  const float* fc_b = (const float*)d_in[6];

  init_ht<<<512, 256, 0, stream>>>();  // zero 2 MB of tagged words (agent scope)
  gru_persistent<<<NCL * NWG, 256, 0, stream>>>(x, w_ih, w_hh, b_ih, b_hh,
                                                fc_w, fc_b, (float*)d_out);
}

// Round 14
// 1975.879 us; speedup vs baseline: 1.6568x; 1.6568x over previous
//
#include <hip/hip_runtime.h>
#include <hip/hip_bf16.h>

#define B_ 256
#define T_ 512
#define F_ 8
#define H_ 512
#define OUT_ 96

// 16 batch-clusters x (8 workgroups x 4 waves). Each wave owns 16 h-cols
// (48 gate-cols), W slice register-resident. 128 blocks of 256 thr =>
// co-residency guaranteed by capacity. Exchange: round-8 flag protocol
// (8 per-wg flags in one 64B line, sleep-backoff poll) with the publish
// path de-serialized: wave-local transpose + own vmcnt drain + LDS counter;
// 4th wave stores the wg flag. ONE workgroup barrier per step.
#define NCL 16
#define BT 16
#define NWG 8

typedef __attribute__((ext_vector_type(8))) short short8;
typedef __attribute__((ext_vector_type(4))) float f32x4;

// g_hbuf: [buf][chunk=col>>3][row][2 u64]  (16B = 8 bf16 cols per (chunk,row))
__device__ unsigned long long g_hbuf[2ull * 64 * 256 * 2];
// per-cluster flag block: 8 u32 packed in ONE 64B line (single-request poll)
__device__ __align__(64) unsigned g_flag[NCL * 16];

__device__ __forceinline__ short f2bf(float v) {
  __hip_bfloat16 b = __float2bfloat16(v);
  unsigned short u;
  __builtin_memcpy(&u, &b, 2);
  return (short)u;
}

__device__ __forceinline__ size_t hidx(int buf, int chunk, int row) {
  return ((size_t)((buf * 64 + chunk) * 256 + row)) * 2;
}

__global__ void init_flags() {
  int i = blockIdx.x * 256 + (int)threadIdx.x;
  if (i < NCL * 16) g_flag[i] = 0;
}

__global__ __launch_bounds__(256, 1) void gru_persistent(
    const float* x, const float* w_ih, const float* w_hh,
    const float* bias_ih, const float* bias_hh,
    const float* fc_w, const float* fc_b, float* out) {
  const int tid = (int)threadIdx.x;
  const int w = tid >> 6;
  const int lane = tid & 63;
  const int l15 = lane & 15;
  const int lg = lane >> 4;
  const int bid = (int)blockIdx.x;
  const int cl = bid & 15;   // cluster
  const int wgj = bid >> 4;  // wg within cluster
  const int rb0 = cl * BT;
  const int c0 = wgj * 64 + w * 16;

  __shared__ short8 h_lds[1024];    // [chunk*16 + localrow] 16B blocks (16 KB)
  __shared__ short t_hw[4][16][20]; // per-WAVE transpose tiles (40B rows, 8B-mult)
  __shared__ unsigned pubcnt;       // publish counter (monotone, 4 per step)

  if (tid == 0) pubcnt = 0;

  // ---- W fragments, register-resident for all 512 steps ----
  short8 wfrag[3][17];
#pragma unroll
  for (int g = 0; g < 3; ++g) {
    const float* wr = w_hh + (size_t)(g * H_ + c0 + l15) * H_ + lg * 8;
#pragma unroll
    for (int kk = 0; kk < 16; ++kk) {
      f32x4 a = ((const f32x4*)(wr + kk * 32))[0];
      f32x4 b2 = ((const f32x4*)(wr + kk * 32))[1];
      short8 o;
#pragma unroll
      for (int j = 0; j < 4; ++j) { o[j] = f2bf(a[j]); o[4 + j] = f2bf(b2[j]); }
      wfrag[g][kk] = o;
    }
    short8 o = {0, 0, 0, 0, 0, 0, 0, 0};
    if (lg == 0) {  // k = 512..519 -> W_ih row
      const f32x4* wi = (const f32x4*)(w_ih + (size_t)(g * H_ + c0 + l15) * F_);
      f32x4 a = wi[0], b2 = wi[1];
#pragma unroll
      for (int j = 0; j < 4; ++j) { o[j] = f2bf(a[j]); o[4 + j] = f2bf(b2[j]); }
    }
    wfrag[g][16] = o;
  }

  const int colh = c0 + l15;
  const float b_r = bias_ih[colh] + bias_hh[colh];
  const float b_z = bias_ih[H_ + colh] + bias_hh[H_ + colh];
  const float bin_ = bias_ih[2 * H_ + colh];
  const float bhn_ = bias_hh[2 * H_ + colh];

  float hown[4] = {0.f, 0.f, 0.f, 0.f};
  bool gaveup = false;

  const int hrow = rb0 + l15;
  const float* xrow = x + (size_t)hrow * T_ * F_;

  // publish geometry: lane -> local row = lane>>2, 4 cols at c0 + (lane&3)*4
  const int prow = lane >> 2;
  const int pcq = lane & 3;

  __syncthreads();  // pubcnt + (first-step trivial h_lds state) ready

  // x prefetch for t=0
  f32x4 xa = ((const f32x4*)xrow)[0];
  f32x4 xb2 = ((const f32x4*)xrow)[1];

  for (int t = 0; t < T_; ++t) {
    // ---- x fragment + hoisted x-MFMAs (independent of the gather) ----
    short8 xf;
#pragma unroll
    for (int j = 0; j < 4; ++j) { xf[j] = f2bf(xa[j]); xf[4 + j] = f2bf(xb2[j]); }
    f32x4 acc_r = {0.f, 0.f, 0.f, 0.f}, acc_z = {0.f, 0.f, 0.f, 0.f};
    f32x4 acc_nh = {0.f, 0.f, 0.f, 0.f}, acc_nx = {0.f, 0.f, 0.f, 0.f};
    acc_r = __builtin_amdgcn_mfma_f32_16x16x32_bf16(xf, wfrag[0][16], acc_r, 0, 0, 0);
    acc_z = __builtin_amdgcn_mfma_f32_16x16x32_bf16(xf, wfrag[1][16], acc_z, 0, 0, 0);
    acc_nx = __builtin_amdgcn_mfma_f32_16x16x32_bf16(xf, wfrag[2][16], acc_nx, 0, 0, 0);

    if (t > 0) {
      // ---- poll: ONE coalesced line-load per wave, __all exit, sleep(1) ----
      if (!gaveup) {
        unsigned spins = 0;
        for (;;) {
          unsigned f = __hip_atomic_load(&g_flag[cl * 16 + (lane & 7)],
                                         __ATOMIC_RELAXED, __HIP_MEMORY_SCOPE_AGENT);
          if (__all((int)(f >= (unsigned)t))) break;
          __builtin_amdgcn_s_sleep(1);
          if (++spins > (1u << 20)) { gaveup = true; break; }
        }
        __builtin_amdgcn_sched_barrier(0);  // gathers issue only after poll exit
      }
      // ---- cooperative gather, lane-linear (conflict-free LDS writes) ----
      const int buf = t & 1;
#pragma unroll
      for (int r4 = 0; r4 < 4; ++r4) {
        const int idx = r4 * 256 + tid;     // 0..1023
        size_t i0 = hidx(buf, idx >> 4, rb0 + (idx & 15));
        unsigned long long q0 = __hip_atomic_load(&g_hbuf[i0], __ATOMIC_RELAXED,
                                                  __HIP_MEMORY_SCOPE_AGENT);
        unsigned long long q1 = __hip_atomic_load(&g_hbuf[i0 + 1], __ATOMIC_RELAXED,
                                                  __HIP_MEMORY_SCOPE_AGENT);
        union { unsigned long long q[2]; short8 s; } u;
        u.q[0] = q0; u.q[1] = q1;
        h_lds[idx] = u.s;
      }
    }

    __syncthreads();  // the ONLY barrier per step (gather writes -> frag reads)

    // prefetch x for t+1 (overlaps MFMA)
    {
      const int tn = (t + 1 < T_) ? t + 1 : T_ - 1;
      xa = ((const f32x4*)(xrow + (size_t)tn * F_))[0];
      xb2 = ((const f32x4*)(xrow + (size_t)tn * F_))[1];
    }

    // ---- h MFMAs: 3 gates per kk ----
    if (t > 0) {
#pragma unroll
      for (int kk = 0; kk < 16; ++kk) {
        short8 a = h_lds[(kk * 4 + lg) * 16 + l15];
        acc_r = __builtin_amdgcn_mfma_f32_16x16x32_bf16(a, wfrag[0][kk], acc_r, 0, 0, 0);
        acc_z = __builtin_amdgcn_mfma_f32_16x16x32_bf16(a, wfrag[1][kk], acc_z, 0, 0, 0);
        acc_nh = __builtin_amdgcn_mfma_f32_16x16x32_bf16(a, wfrag[2][kk], acc_nh, 0, 0, 0);
      }
    }

    // ---- gates + fp32-carry state update ----
    short hnew[4];
#pragma unroll
    for (int q = 0; q < 4; ++q) {
      float pr = acc_r[q] + b_r;
      float pz = acc_z[q] + b_z;
      float r = 1.f / (1.f + __expf(-pr));
      float z = 1.f / (1.f + __expf(-pz));
      float n = tanhf(acc_nx[q] + bin_ + r * (acc_nh[q] + bhn_));
      hown[q] = n + z * (hown[q] - n);
      hnew[q] = f2bf(hown[q]);
    }

    // ---- wave-local transpose (same-wave LDS ordering; no barrier) ----
#pragma unroll
    for (int q = 0; q < 4; ++q) t_hw[w][4 * lg + q][l15] = hnew[q];
    // ---- wave-local publish: one u64 agent-scope store per lane ----
    {
      unsigned long long v;
      __builtin_memcpy(&v, &t_hw[w][prow][pcq * 4], 8);
      const int colg = c0 + pcq * 4;
      size_t i0 = hidx((t + 1) & 1, colg >> 3, rb0 + prow) + ((colg >> 2) & 1);
      __hip_atomic_store(&g_hbuf[i0], v, __ATOMIC_RELAXED, __HIP_MEMORY_SCOPE_AGENT);
    }
    // drain THIS wave's stores to the coherence point, then count in LDS;
    // the 4th wave of the wg stores the wg flag (replaces two barriers)
    asm volatile("s_waitcnt vmcnt(0)" ::: "memory");
    if (lane == 0) {
      unsigned c = atomicAdd(&pubcnt, 1u);  // LDS atomic, returns old
      if (c == (unsigned)(4 * t + 3))
        __hip_atomic_store(&g_flag[cl * 16 + wgj], (unsigned)(t + 1),
                           __ATOMIC_RELAXED, __HIP_MEMORY_SCOPE_AGENT);
    }
  }

  // ---- final FC: 6 waves per cluster cover the 96 output columns ----
  const int wi = wgj * 4 + w;
  if (wi >= OUT_ / 16) return;
  if (!gaveup) {
    unsigned spins = 0;
    for (;;) {
      unsigned f = __hip_atomic_load(&g_flag[cl * 16 + (lane & 7)],
                                     __ATOMIC_RELAXED, __HIP_MEMORY_SCOPE_AGENT);
      if (__all((int)(f >= (unsigned)T_))) break;
      __builtin_amdgcn_s_sleep(1);
      if (++spins > (1u << 20)) break;
    }
    __builtin_amdgcn_fence(__ATOMIC_ACQUIRE, "agent");  // once, cheap
  }
  short8 afrag[16];
#pragma unroll
  for (int kk = 0; kk < 16; ++kk) {  // h_512 is in buffer (512 & 1) == 0
    size_t i0 = hidx(0, kk * 4 + lg, hrow);
    unsigned long long q0 =
        __hip_atomic_load(&g_hbuf[i0], __ATOMIC_RELAXED, __HIP_MEMORY_SCOPE_AGENT);
    unsigned long long q1 =
        __hip_atomic_load(&g_hbuf[i0 + 1], __ATOMIC_RELAXED, __HIP_MEMORY_SCOPE_AGENT);
    union { unsigned long long q[2]; short8 s; } u;
    u.q[0] = q0; u.q[1] = q1;
    afrag[kk] = u.s;
  }
  const int col = wi * 16 + l15;
  const float* wrow = fc_w + (size_t)col * H_ + lg * 8;
  f32x4 acc = {0.f, 0.f, 0.f, 0.f};
#pragma unroll
  for (int kk = 0; kk < 16; ++kk) {
    f32x4 a = ((const f32x4*)(wrow + kk * 32))[0];
    f32x4 b2 = ((const f32x4*)(wrow + kk * 32))[1];
    short8 bfr;
#pragma unroll
    for (int j = 0; j < 4; ++j) { bfr[j] = f2bf(a[j]); bfr[4 + j] = f2bf(b2[j]); }
    acc = __builtin_amdgcn_mfma_f32_16x16x32_bf16(afrag[kk], bfr, acc, 0, 0, 0);
  }
  const float fb = fc_b[col];
#pragma unroll
  for (int q = 0; q < 4; ++q) {
    int row_o = rb0 + lg * 4 + q;
    out[(size_t)row_o * OUT_ + col] = acc[q] + fb;
  }
}

extern "C" void kernel_launch(void* const* d_in, const int* in_sizes, int n_in,
                              void* d_out, int out_size, void* d_ws, size_t ws_size,
                              hipStream_t stream) {
  const float* x = (const float*)d_in[0];
  const float* w_ih = (const float*)d_in[1];
  const float* w_hh = (const float*)d_in[2];
  const float* b_ih = (const float*)d_in[3];
  const float* b_hh = (const float*)d_in[4];
  const float* fc_w = (const float*)d_in[5];
  const float* fc_b = (const float*)d_in[6];

  init_flags<<<1, 256, 0, stream>>>();
  gru_persistent<<<NCL * NWG, 256, 0, stream>>>(x, w_ih, w_hh, b_ih, b_hh,
                                                fc_w, fc_b, (float*)d_out);
}